// Round 1
// baseline (715.692 us; speedup 1.0000x reference)
//
#include <hip/hip_runtime.h>

namespace {

constexpr int H = 128;
constexpr int N = 200;
constexpr int BN = 1600;          // B*N
constexpr int X_SIZE = BN * H;    // 204800

// ws offsets (floats)
constexpr int WS_VX   = 0;
constexpr int WS_UX   = WS_VX + X_SIZE;
constexpr int WS_VXN  = WS_UX + X_SIZE;
constexpr int WS_XTMP = WS_VXN + X_SIZE;
constexpr int WS_AGG  = WS_XTMP + X_SIZE;
constexpr int WS_ESUM = WS_AGG + X_SIZE;
constexpr int WS_ESSQ = WS_ESUM + H;
constexpr int WS_NSUM = WS_ESSQ + H;
constexpr int WS_NSSQ = WS_NSUM + H;
constexpr int WS_CNT  = WS_NSSQ + H;   // [0]=cnt_e, [1]=cnt_n
constexpr int WS_ESC  = WS_CNT + 4;
constexpr int WS_ESH  = WS_ESC + H;
constexpr int WS_NSC  = WS_ESH + H;
constexpr int WS_NSH  = WS_NSC + H;

// ---- counts: cnt_n = sum(mask); cnt_e = sum_b (sum_i m[b,i])^2 ----
__global__ void k_cnt(const int* __restrict__ mask, float* __restrict__ ws) {
  __shared__ float sb[8];
  const int t = threadIdx.x;          // 256 threads
  const int b = t >> 5, li = t & 31;
  float s = 0.f;
  for (int i = li; i < N; i += 32) s += (float)mask[b * N + i];
  #pragma unroll
  for (int o = 16; o >= 1; o >>= 1) s += __shfl_down(s, o, 32);
  if (li == 0) sb[b] = s;
  __syncthreads();
  if (t == 0) {
    float cn = 0.f, ce = 0.f;
    #pragma unroll
    for (int bb = 0; bb < 8; ++bb) { cn += sb[bb]; ce += sb[bb] * sb[bb]; }
    ws[WS_CNT + 0] = fmaxf(ce, 1.f);
    ws[WS_CNT + 1] = fmaxf(cn, 1.f);
  }
}

// ---- node linears: Vx, Ux, Vxn (masked) ----
__global__ __launch_bounds__(128) void k_prep(
    const float* __restrict__ x, const int* __restrict__ mask,
    const float* __restrict__ VeW, const float* __restrict__ Veb,
    const float* __restrict__ UnW, const float* __restrict__ Unb,
    const float* __restrict__ VnW, const float* __restrict__ Vnb,
    float* __restrict__ ws) {
  const int bi = blockIdx.x, h = threadIdx.x;
  __shared__ float xr[H];
  xr[h] = x[bi * H + h];
  __syncthreads();
  const float mi = (float)mask[bi];
  float a0 = 0.f, a1 = 0.f, a2 = 0.f;
  #pragma unroll 4
  for (int k = 0; k < H; k += 4) {
    const float x0 = xr[k], x1 = xr[k + 1], x2 = xr[k + 2], x3 = xr[k + 3];
    float4 w;
    w = *(const float4*)&VeW[h * H + k];
    a0 += w.x * x0 + w.y * x1 + w.z * x2 + w.w * x3;
    w = *(const float4*)&UnW[h * H + k];
    a1 += w.x * x0 + w.y * x1 + w.z * x2 + w.w * x3;
    w = *(const float4*)&VnW[h * H + k];
    a2 += w.x * x0 + w.y * x1 + w.z * x2 + w.w * x3;
  }
  ws[WS_VX  + bi * H + h] = mi * (a0 + Veb[h]);
  ws[WS_UX  + bi * H + h] = mi * (a1 + Unb[h]);
  ws[WS_VXN + bi * H + h] = mi * (a2 + Vnb[h]);
}

// ---- big fused pass over e. PASS 0: stats+agg. PASS 1: normalize+residual+write ----
template <int PASS>
__global__ __launch_bounds__(512) void k_pass(
    const float* __restrict__ e, const int* __restrict__ mask,
    const float* __restrict__ UeW, const float* __restrict__ Ueb,
    float* __restrict__ ws, float* __restrict__ out) {
  const int bi = blockIdx.x;
  const int b = bi / N;
  const int tid = threadIdx.x;
  const int tj = tid & 15, th = tid >> 4;   // 16 x 32 thread grid
  const int j0 = tj * 4, h0 = th * 4;       // thread tile 4j x 4h

  __shared__ float et[H * 68];   // e-tile transposed [k][j], stride 68 (f4-aligned, pad)
  __shared__ float mrow[N];

  for (int j = tid; j < N; j += 512) mrow[j] = (float)mask[b * N + j];

  const float* __restrict__ eg = e + (size_t)bi * (N * H);
  const float mi = (float)mask[bi];

  float base[4];
  {
    const float4 vxi = *(const float4*)&ws[WS_VX + bi * H + h0];
    const float4 ub  = *(const float4*)&Ueb[h0];
    base[0] = ub.x + vxi.x; base[1] = ub.y + vxi.y;
    base[2] = ub.z + vxi.z; base[3] = ub.w + vxi.w;
  }
  float sc[4] = {0, 0, 0, 0}, sh[4] = {0, 0, 0, 0};
  if (PASS == 1) {
    const float4 s1 = *(const float4*)&ws[WS_ESC + h0];
    const float4 s2 = *(const float4*)&ws[WS_ESH + h0];
    sc[0] = s1.x; sc[1] = s1.y; sc[2] = s1.z; sc[3] = s1.w;
    sh[0] = s2.x; sh[1] = s2.y; sh[2] = s2.z; sh[3] = s2.w;
  }
  float bnS[4] = {0, 0, 0, 0}, bnS2[4] = {0, 0, 0, 0}, ag[4] = {0, 0, 0, 0};

  for (int jc = 0; jc < 4; ++jc) {
    const int jbase = jc * 64;
    const int JJ = (jbase + 64 <= N) ? 64 : (N - jbase);   // 64,64,64,8
    __syncthreads();   // previous k-loop done before restaging et
    for (int idx = tid; idx < JJ * H; idx += 512) {
      const int jj = idx >> 7, kk = idx & 127;
      et[kk * 68 + jj] = eg[(size_t)(jbase + jj) * H + kk];
    }
    __syncthreads();

    float acc[4][4] = {{0,0,0,0},{0,0,0,0},{0,0,0,0},{0,0,0,0}};
    #pragma unroll 2
    for (int kq = 0; kq < 32; ++kq) {
      const int k = kq * 4;
      const float4 e0 = *(const float4*)&et[(k + 0) * 68 + j0];
      const float4 e1 = *(const float4*)&et[(k + 1) * 68 + j0];
      const float4 e2 = *(const float4*)&et[(k + 2) * 68 + j0];
      const float4 e3 = *(const float4*)&et[(k + 3) * 68 + j0];
      const float ea0[4] = {e0.x, e0.y, e0.z, e0.w};
      const float ea1[4] = {e1.x, e1.y, e1.z, e1.w};
      const float ea2[4] = {e2.x, e2.y, e2.z, e2.w};
      const float ea3[4] = {e3.x, e3.y, e3.z, e3.w};
      #pragma unroll
      for (int hh = 0; hh < 4; ++hh) {
        const float4 w = *(const float4*)&UeW[(h0 + hh) * H + k];  // L1/L2-hot
        #pragma unroll
        for (int jj = 0; jj < 4; ++jj) {
          acc[jj][hh] += ea0[jj] * w.x + ea1[jj] * w.y + ea2[jj] * w.z + ea3[jj] * w.w;
        }
      }
    }

    #pragma unroll
    for (int jj = 0; jj < 4; ++jj) {
      const int j = jbase + j0 + jj;
      if (j >= N) break;
      const float msk = mi * mrow[j];
      const int row = (b * N + j) * H + h0;
      const float4 vxj4 = *(const float4*)&ws[WS_VX + row];
      const float vxj[4] = {vxj4.x, vxj4.y, vxj4.z, vxj4.w};
      if (PASS == 0) {
        const float4 vxn4 = *(const float4*)&ws[WS_VXN + row];
        const float vxn[4] = {vxn4.x, vxn4.y, vxn4.z, vxn4.w};
        #pragma unroll
        for (int hh = 0; hh < 4; ++hh) {
          const float v = acc[jj][hh] + base[hh] + vxj[hh];
          bnS[hh]  += msk * v;
          bnS2[hh] += msk * v * v;
          const float sg = 1.f / (1.f + __expf(-v));
          ag[hh] += msk * sg * vxn[hh];
        }
      } else {
        const size_t er = (size_t)j * H + h0;
        const float4 e4 = *(const float4*)&eg[er];   // residual re-read (cache-hot)
        const float ea[4] = {e4.x, e4.y, e4.z, e4.w};
        float o[4];
        #pragma unroll
        for (int hh = 0; hh < 4; ++hh) {
          const float v = acc[jj][hh] + base[hh] + vxj[hh];
          const float r = (msk > 0.f) ? (v * sc[hh] + sh[hh]) : v;
          o[hh] = ea[hh] + fmaxf(r, 0.f);
        }
        *(float4*)&out[(size_t)X_SIZE + (size_t)bi * (N * H) + er] =
            make_float4(o[0], o[1], o[2], o[3]);
      }
    }
  }

  if (PASS == 0) {
    // reduce over tj (16-lane groups within each wave)
    #pragma unroll
    for (int hh = 0; hh < 4; ++hh) {
      #pragma unroll
      for (int mm = 8; mm >= 1; mm >>= 1) {
        bnS[hh]  += __shfl_xor(bnS[hh],  mm, 16);
        bnS2[hh] += __shfl_xor(bnS2[hh], mm, 16);
        ag[hh]   += __shfl_xor(ag[hh],   mm, 16);
      }
    }
    if (tj == 0) {
      #pragma unroll
      for (int hh = 0; hh < 4; ++hh) {
        const int h = h0 + hh;
        atomicAdd(&ws[WS_ESUM + h], bnS[hh]);
        atomicAdd(&ws[WS_ESSQ + h], bnS2[hh]);
        ws[WS_AGG + bi * H + h] = ag[hh];   // unique per block: plain store
      }
    }
  }
}

// ---- x_tmp = Ux + agg; node BN partial sums ----
__global__ void k_x1(const int* __restrict__ mask, float* __restrict__ ws) {
  const int t = blockIdx.x * 256 + threadIdx.x;   // 50*256 = 12800
  const int h = t & 127, g = t >> 7;              // g 0..99
  float s = 0.f, s2 = 0.f;
  for (int bi = g; bi < BN; bi += 100) {
    const float v = ws[WS_UX + bi * H + h] + ws[WS_AGG + bi * H + h];
    ws[WS_XTMP + bi * H + h] = v;
    if (mask[bi] != 0) { s += v; s2 += v * v; }
  }
  atomicAdd(&ws[WS_NSUM + h], s);
  atomicAdd(&ws[WS_NSSQ + h], s2);
}

// ---- finalize BN scale/shift for edge and node ----
__global__ void k_stats(const float* __restrict__ beg, const float* __restrict__ beb,
                        const float* __restrict__ bng, const float* __restrict__ bnb,
                        float* __restrict__ ws) {
  const int h = threadIdx.x;   // 128
  const float ce = ws[WS_CNT + 0], cn = ws[WS_CNT + 1];
  const float me = ws[WS_ESUM + h] / ce;
  const float ve = fmaxf(ws[WS_ESSQ + h] / ce - me * me, 0.f);
  const float se = rsqrtf(ve + 1e-5f) * beg[h];
  ws[WS_ESC + h] = se;
  ws[WS_ESH + h] = beb[h] - me * se;
  const float mn = ws[WS_NSUM + h] / cn;
  const float vn = fmaxf(ws[WS_NSSQ + h] / cn - mn * mn, 0.f);
  const float sn = rsqrtf(vn + 1e-5f) * bng[h];
  ws[WS_NSC + h] = sn;
  ws[WS_NSH + h] = bnb[h] - mn * sn;
}

// ---- x_new = x + relu(masked BN(x_tmp)) ----
__global__ void k_x2(const float* __restrict__ x, const int* __restrict__ mask,
                     const float* __restrict__ ws, float* __restrict__ out) {
  const int idx = blockIdx.x * 256 + threadIdx.x;
  if (idx >= X_SIZE) return;
  const int h = idx & 127, bi = idx >> 7;
  const float v = ws[WS_XTMP + idx];
  const float r = (mask[bi] != 0) ? (v * ws[WS_NSC + h] + ws[WS_NSH + h]) : v;
  out[idx] = x[idx] + fmaxf(r, 0.f);
}

}  // namespace

extern "C" void kernel_launch(void* const* d_in, const int* in_sizes, int n_in,
                              void* d_out, int out_size, void* d_ws, size_t ws_size,
                              hipStream_t stream) {
  const float* x    = (const float*)d_in[0];
  const float* e    = (const float*)d_in[1];
  const int*   mask = (const int*)d_in[2];
  const float* UeW  = (const float*)d_in[3];
  const float* Ueb  = (const float*)d_in[4];
  const float* VeW  = (const float*)d_in[5];
  const float* Veb  = (const float*)d_in[6];
  const float* UnW  = (const float*)d_in[7];
  const float* Unb  = (const float*)d_in[8];
  const float* VnW  = (const float*)d_in[9];
  const float* Vnb  = (const float*)d_in[10];
  const float* bng  = (const float*)d_in[11];
  const float* bnb  = (const float*)d_in[12];
  const float* beg  = (const float*)d_in[13];
  const float* beb  = (const float*)d_in[14];
  float* ws  = (float*)d_ws;
  float* out = (float*)d_out;

  // zero the 4 contiguous stat accumulators (ESUM,ESSQ,NSUM,NSSQ)
  hipMemsetAsync(ws + WS_ESUM, 0, 4 * H * sizeof(float), stream);
  k_cnt<<<1, 256, 0, stream>>>(mask, ws);
  k_prep<<<BN, 128, 0, stream>>>(x, mask, VeW, Veb, UnW, Unb, VnW, Vnb, ws);
  k_pass<0><<<BN, 512, 0, stream>>>(e, mask, UeW, Ueb, ws, out);
  k_x1<<<50, 256, 0, stream>>>(mask, ws);
  k_stats<<<1, 128, 0, stream>>>(beg, beb, bng, bnb, ws);
  k_x2<<<800, 256, 0, stream>>>(x, mask, ws, out);
  k_pass<1><<<BN, 512, 0, stream>>>(e, mask, UeW, Ueb, ws, out);
}

// Round 2
// 313.162 us; speedup vs baseline: 2.2854x; 2.2854x over previous
//
#include <hip/hip_runtime.h>

namespace {

typedef __attribute__((ext_vector_type(8))) short short8;
typedef __attribute__((ext_vector_type(4))) float f32x4;

constexpr int H = 128;
constexpr int N = 200;
constexpr int BN = 1600;          // B*N
constexpr int X_SIZE = BN * H;    // 204800
constexpr int NH = N * H;         // 25600

// ws offsets (floats)
constexpr int WS_VX   = 0;
constexpr int WS_UX   = WS_VX + X_SIZE;
constexpr int WS_VXN  = WS_UX + X_SIZE;
constexpr int WS_XTMP = WS_VXN + X_SIZE;
constexpr int WS_AGG  = WS_XTMP + X_SIZE;
constexpr int WS_ESUM = WS_AGG + X_SIZE;
constexpr int WS_ESSQ = WS_ESUM + H;
constexpr int WS_NSUM = WS_ESSQ + H;
constexpr int WS_NSSQ = WS_NSUM + H;
constexpr int WS_CNT  = WS_NSSQ + H;   // [0]=cnt_e, [1]=cnt_n
constexpr int WS_ESC  = WS_CNT + 4;
constexpr int WS_ESH  = WS_ESC + H;
constexpr int WS_NSC  = WS_ESH + H;
constexpr int WS_NSH  = WS_NSC + H;

__device__ __forceinline__ unsigned short f2bf(float f) {
  const unsigned u = __float_as_uint(f);
  return (unsigned short)((u + 0x7fffu + ((u >> 16) & 1u)) >> 16);  // RNE
}

__device__ __forceinline__ short8 pack8(float4 a, float4 b) {
  short8 r;
  r[0] = (short)f2bf(a.x); r[1] = (short)f2bf(a.y);
  r[2] = (short)f2bf(a.z); r[3] = (short)f2bf(a.w);
  r[4] = (short)f2bf(b.x); r[5] = (short)f2bf(b.y);
  r[6] = (short)f2bf(b.z); r[7] = (short)f2bf(b.w);
  return r;
}

// ---- counts: cnt_n = sum(mask); cnt_e = sum_b (sum_i m[b,i])^2 ----
__global__ void k_cnt(const int* __restrict__ mask, float* __restrict__ ws) {
  __shared__ float sb[8];
  const int t = threadIdx.x;          // 256 threads
  const int b = t >> 5, li = t & 31;
  float s = 0.f;
  for (int i = li; i < N; i += 32) s += (float)mask[b * N + i];
  #pragma unroll
  for (int o = 16; o >= 1; o >>= 1) s += __shfl_down(s, o, 32);
  if (li == 0) sb[b] = s;
  __syncthreads();
  if (t == 0) {
    float cn = 0.f, ce = 0.f;
    #pragma unroll
    for (int bb = 0; bb < 8; ++bb) { cn += sb[bb]; ce += sb[bb] * sb[bb]; }
    ws[WS_CNT + 0] = fmaxf(ce, 1.f);
    ws[WS_CNT + 1] = fmaxf(cn, 1.f);
  }
}

// ---- node linears: Vx, Ux, Vxn (masked) ----
__global__ __launch_bounds__(128) void k_prep(
    const float* __restrict__ x, const int* __restrict__ mask,
    const float* __restrict__ VeW, const float* __restrict__ Veb,
    const float* __restrict__ UnW, const float* __restrict__ Unb,
    const float* __restrict__ VnW, const float* __restrict__ Vnb,
    float* __restrict__ ws) {
  const int bi = blockIdx.x, h = threadIdx.x;
  __shared__ float xr[H];
  xr[h] = x[bi * H + h];
  __syncthreads();
  const float mi = (float)mask[bi];
  float a0 = 0.f, a1 = 0.f, a2 = 0.f;
  #pragma unroll 4
  for (int k = 0; k < H; k += 4) {
    const float x0 = xr[k], x1 = xr[k + 1], x2 = xr[k + 2], x3 = xr[k + 3];
    float4 w;
    w = *(const float4*)&VeW[h * H + k];
    a0 += w.x * x0 + w.y * x1 + w.z * x2 + w.w * x3;
    w = *(const float4*)&UnW[h * H + k];
    a1 += w.x * x0 + w.y * x1 + w.z * x2 + w.w * x3;
    w = *(const float4*)&VnW[h * H + k];
    a2 += w.x * x0 + w.y * x1 + w.z * x2 + w.w * x3;
  }
  ws[WS_VX  + bi * H + h] = mi * (a0 + Veb[h]);
  ws[WS_UX  + bi * H + h] = mi * (a1 + Unb[h]);
  ws[WS_VXN + bi * H + h] = mi * (a2 + Vnb[h]);
}

// ---- big fused MFMA pass over e ----
// PASS 0: e_tmp stats + sigmoid aggregation.  PASS 1: normalize+residual+write.
// Block = one (b,i). 4 waves; wave w owns h-half (w&1)*64 and j-tiles (w>>1)::2.
template <int PASS>
__global__ __launch_bounds__(256) void k_edge(
    const float* __restrict__ e, const int* __restrict__ mask,
    const float* __restrict__ UeW, const float* __restrict__ Ueb,
    float* __restrict__ ws, float* __restrict__ out) {
  const int bi = blockIdx.x;
  const int b = bi / N;
  const int tid = threadIdx.x;
  const int w = tid >> 6, lane = tid & 63;
  const int l15 = lane & 15, lg = lane >> 4;
  const int hbase = (w & 1) * 64;

  __shared__ float mrow[N];
  __shared__ float pS[4][64], pS2[4][64], pA[4][64];

  if (tid < N) mrow[tid] = (float)mask[b * N + tid];
  __syncthreads();

  const float mi = (float)mask[bi];
  const float* __restrict__ eg = e + (size_t)bi * NH;

  // W frags: lane holds W[hbase+ht*16+l15][s*32 + lg*8 + (0..7)]  (bf16)
  // PASS0: used as B operand (B[k][n] = W[n][k]).  PASS1: used as A (A[m][k] = W[m][k]).
  short8 Wf[4][4];
  #pragma unroll
  for (int ht = 0; ht < 4; ++ht) {
    const float* wr = &UeW[(size_t)(hbase + ht * 16 + l15) * H + lg * 8];
    #pragma unroll
    for (int s = 0; s < 4; ++s) {
      const float4 u0 = *(const float4*)(wr + s * 32);
      const float4 u1 = *(const float4*)(wr + s * 32 + 4);
      Wf[ht][s] = pack8(u0, u1);
    }
  }

  // epilogue per-ht constants
  float basev[4];                 // PASS0: h = hbase+ht*16+l15
  float4 base4[4], sc4[4], sh4[4]; // PASS1: h0 = hbase+ht*16+4*lg
  #pragma unroll
  for (int ht = 0; ht < 4; ++ht) {
    if (PASS == 0) {
      const int h = hbase + ht * 16 + l15;
      basev[ht] = Ueb[h] + ws[WS_VX + (size_t)bi * H + h];
    } else {
      const int h0 = hbase + ht * 16 + 4 * lg;
      const float4 ub = *(const float4*)&Ueb[h0];
      const float4 vx = *(const float4*)&ws[WS_VX + (size_t)bi * H + h0];
      base4[ht] = make_float4(ub.x + vx.x, ub.y + vx.y, ub.z + vx.z, ub.w + vx.w);
      sc4[ht] = *(const float4*)&ws[WS_ESC + h0];
      sh4[ht] = *(const float4*)&ws[WS_ESH + h0];
    }
  }

  float bnS[4] = {0.f, 0.f, 0.f, 0.f};
  float bnS2[4] = {0.f, 0.f, 0.f, 0.f};
  float agv[4] = {0.f, 0.f, 0.f, 0.f};

  const short8 zfrag = {0, 0, 0, 0, 0, 0, 0, 0};

  for (int jt = (w >> 1); jt < 13; jt += 2) {
    const int j0 = jt * 16;
    // e frags: lane holds e[j0+l15][s*32 + lg*8 + (0..7)]  (bf16)
    const int jl = j0 + l15;
    const float* er = eg + (size_t)(jl < N ? jl : 0) * H + lg * 8;
    short8 Ef[4];
    #pragma unroll
    for (int s = 0; s < 4; ++s) {
      const float4 u0 = *(const float4*)(er + s * 32);
      const float4 u1 = *(const float4*)(er + s * 32 + 4);
      Ef[s] = pack8(u0, u1);
    }
    if (jl >= N) {
      #pragma unroll
      for (int s = 0; s < 4; ++s) Ef[s] = zfrag;
    }

    f32x4 acc[4] = {f32x4(0.f), f32x4(0.f), f32x4(0.f), f32x4(0.f)};
    #pragma unroll
    for (int s = 0; s < 4; ++s) {
      #pragma unroll
      for (int ht = 0; ht < 4; ++ht) {
        if (PASS == 0)   // D[j][h]: col h = ht*16+l15, row j = j0+4*lg+r
          acc[ht] = __builtin_amdgcn_mfma_f32_16x16x32_bf16(Ef[s], Wf[ht][s], acc[ht], 0, 0, 0);
        else             // D[h][j]: col j = j0+l15, row h = ht*16+4*lg+r
          acc[ht] = __builtin_amdgcn_mfma_f32_16x16x32_bf16(Wf[ht][s], Ef[s], acc[ht], 0, 0, 0);
      }
    }

    if (PASS == 0) {
      #pragma unroll
      for (int r = 0; r < 4; ++r) {
        const int j = j0 + 4 * lg + r;
        if (j >= N) continue;                 // only jt==12, lg>=2
        const float msk = mi * mrow[j];
        const size_t row = (size_t)(b * N + j) * H;
        #pragma unroll
        for (int ht = 0; ht < 4; ++ht) {
          const int h = hbase + ht * 16 + l15;
          const float v = acc[ht][r] + basev[ht] + ws[WS_VX + row + h];
          bnS[ht]  += msk * v;
          bnS2[ht] += msk * v * v;
          const float sg = __builtin_amdgcn_rcpf(1.f + __expf(-v));
          agv[ht] += msk * sg * ws[WS_VXN + row + h];
        }
      }
    } else {
      const int j = j0 + l15;
      if (j < N) {
        const float msk = mi * mrow[j];
        const size_t vrow = (size_t)(b * N + j) * H;
        const size_t erow = (size_t)j * H;
        float* __restrict__ og = out + (size_t)X_SIZE + (size_t)bi * NH + erow;
        #pragma unroll
        for (int ht = 0; ht < 4; ++ht) {
          const int h0 = hbase + ht * 16 + 4 * lg;
          const float4 vx4 = *(const float4*)&ws[WS_VX + vrow + h0];
          const float4 eo4 = *(const float4*)&eg[erow + h0];
          const float vv[4] = {acc[ht][0] + base4[ht].x + vx4.x,
                               acc[ht][1] + base4[ht].y + vx4.y,
                               acc[ht][2] + base4[ht].z + vx4.z,
                               acc[ht][3] + base4[ht].w + vx4.w};
          const float scv[4] = {sc4[ht].x, sc4[ht].y, sc4[ht].z, sc4[ht].w};
          const float shv[4] = {sh4[ht].x, sh4[ht].y, sh4[ht].z, sh4[ht].w};
          const float ev[4] = {eo4.x, eo4.y, eo4.z, eo4.w};
          float o[4];
          #pragma unroll
          for (int r = 0; r < 4; ++r) {
            const float rr = (msk > 0.f) ? (vv[r] * scv[r] + shv[r]) : vv[r];
            o[r] = ev[r] + fmaxf(rr, 0.f);
          }
          *(float4*)&og[h0] = make_float4(o[0], o[1], o[2], o[3]);
        }
      }
    }
  }

  if (PASS == 0) {
    // reduce over the 4 j-row groups (lane bits 4,5), then lane keeps ht==lg slot
    #pragma unroll
    for (int ht = 0; ht < 4; ++ht) {
      bnS[ht]  += __shfl_xor(bnS[ht], 16);  bnS[ht]  += __shfl_xor(bnS[ht], 32);
      bnS2[ht] += __shfl_xor(bnS2[ht], 16); bnS2[ht] += __shfl_xor(bnS2[ht], 32);
      agv[ht]  += __shfl_xor(agv[ht], 16);  agv[ht]  += __shfl_xor(agv[ht], 32);
    }
    float vS = bnS[0], vS2 = bnS2[0], vA = agv[0];
    if (lg == 1) { vS = bnS[1]; vS2 = bnS2[1]; vA = agv[1]; }
    if (lg == 2) { vS = bnS[2]; vS2 = bnS2[2]; vA = agv[2]; }
    if (lg == 3) { vS = bnS[3]; vS2 = bnS2[3]; vA = agv[3]; }
    pS[w][lane] = vS; pS2[w][lane] = vS2; pA[w][lane] = vA;  // lane = (h - hbase)
    __syncthreads();
    if (tid < H) {
      const int p = tid >> 6, hh = tid & 63;   // waves {p, p+2} own this h-half
      const float s1 = pS[p][hh] + pS[p + 2][hh];
      const float s2 = pS2[p][hh] + pS2[p + 2][hh];
      const float s3 = pA[p][hh] + pA[p + 2][hh];
      atomicAdd(&ws[WS_ESUM + tid], s1);
      atomicAdd(&ws[WS_ESSQ + tid], s2);
      ws[WS_AGG + (size_t)bi * H + tid] = s3;   // block-unique: plain store
    }
  }
}

// ---- x_tmp = Ux + agg; node BN partial sums ----
__global__ void k_x1(const int* __restrict__ mask, float* __restrict__ ws) {
  const int t = blockIdx.x * 256 + threadIdx.x;   // 50*256 = 12800
  const int h = t & 127, g = t >> 7;              // g 0..99
  float s = 0.f, s2 = 0.f;
  for (int bi = g; bi < BN; bi += 100) {
    const float v = ws[WS_UX + bi * H + h] + ws[WS_AGG + bi * H + h];
    ws[WS_XTMP + bi * H + h] = v;
    if (mask[bi] != 0) { s += v; s2 += v * v; }
  }
  atomicAdd(&ws[WS_NSUM + h], s);
  atomicAdd(&ws[WS_NSSQ + h], s2);
}

// ---- finalize BN scale/shift for edge and node ----
__global__ void k_stats(const float* __restrict__ beg, const float* __restrict__ beb,
                        const float* __restrict__ bng, const float* __restrict__ bnb,
                        float* __restrict__ ws) {
  const int h = threadIdx.x;   // 128
  const float ce = ws[WS_CNT + 0], cn = ws[WS_CNT + 1];
  const float me = ws[WS_ESUM + h] / ce;
  const float ve = fmaxf(ws[WS_ESSQ + h] / ce - me * me, 0.f);
  const float se = rsqrtf(ve + 1e-5f) * beg[h];
  ws[WS_ESC + h] = se;
  ws[WS_ESH + h] = beb[h] - me * se;
  const float mn = ws[WS_NSUM + h] / cn;
  const float vn = fmaxf(ws[WS_NSSQ + h] / cn - mn * mn, 0.f);
  const float sn = rsqrtf(vn + 1e-5f) * bng[h];
  ws[WS_NSC + h] = sn;
  ws[WS_NSH + h] = bnb[h] - mn * sn;
}

// ---- x_new = x + relu(masked BN(x_tmp)) ----
__global__ void k_x2(const float* __restrict__ x, const int* __restrict__ mask,
                     const float* __restrict__ ws, float* __restrict__ out) {
  const int idx = blockIdx.x * 256 + threadIdx.x;
  if (idx >= X_SIZE) return;
  const int h = idx & 127, bi = idx >> 7;
  const float v = ws[WS_XTMP + idx];
  const float r = (mask[bi] != 0) ? (v * ws[WS_NSC + h] + ws[WS_NSH + h]) : v;
  out[idx] = x[idx] + fmaxf(r, 0.f);
}

}  // namespace

extern "C" void kernel_launch(void* const* d_in, const int* in_sizes, int n_in,
                              void* d_out, int out_size, void* d_ws, size_t ws_size,
                              hipStream_t stream) {
  const float* x    = (const float*)d_in[0];
  const float* e    = (const float*)d_in[1];
  const int*   mask = (const int*)d_in[2];
  const float* UeW  = (const float*)d_in[3];
  const float* Ueb  = (const float*)d_in[4];
  const float* VeW  = (const float*)d_in[5];
  const float* Veb  = (const float*)d_in[6];
  const float* UnW  = (const float*)d_in[7];
  const float* Unb  = (const float*)d_in[8];
  const float* VnW  = (const float*)d_in[9];
  const float* Vnb  = (const float*)d_in[10];
  const float* bng  = (const float*)d_in[11];
  const float* bnb  = (const float*)d_in[12];
  const float* beg  = (const float*)d_in[13];
  const float* beb  = (const float*)d_in[14];
  float* ws  = (float*)d_ws;
  float* out = (float*)d_out;

  // zero the 4 contiguous stat accumulators (ESUM,ESSQ,NSUM,NSSQ)
  hipMemsetAsync(ws + WS_ESUM, 0, 4 * H * sizeof(float), stream);
  k_cnt<<<1, 256, 0, stream>>>(mask, ws);
  k_prep<<<BN, 128, 0, stream>>>(x, mask, VeW, Veb, UnW, Unb, VnW, Vnb, ws);
  k_edge<0><<<BN, 256, 0, stream>>>(e, mask, UeW, Ueb, ws, out);
  k_x1<<<50, 256, 0, stream>>>(mask, ws);
  k_stats<<<1, 128, 0, stream>>>(beg, beb, bng, bnb, ws);
  k_x2<<<800, 256, 0, stream>>>(x, mask, ws, out);
  k_edge<1><<<BN, 256, 0, stream>>>(e, mask, UeW, Ueb, ws, out);
}

// Round 3
// 232.819 us; speedup vs baseline: 3.0740x; 1.3451x over previous
//
#include <hip/hip_runtime.h>
#include <hip/hip_bf16.h>

namespace {

typedef __attribute__((ext_vector_type(8))) short short8;
typedef __attribute__((ext_vector_type(4))) float f32x4;

constexpr int H = 128;
constexpr int N = 200;
constexpr int BN = 1600;          // B*N
constexpr int X_SIZE = BN * H;    // 204800
constexpr int NH = N * H;         // 25600
constexpr long long E_ELEMS = (long long)BN * NH;  // 40,960,000

// ws offsets (floats)
constexpr int WS_VX    = 0;
constexpr int WS_UX    = WS_VX + X_SIZE;
constexpr int WS_VXN   = WS_UX + X_SIZE;
constexpr int WS_XTMP  = WS_VXN + X_SIZE;
constexpr int WS_AGG   = WS_XTMP + X_SIZE;
constexpr int WS_ESUMS = WS_AGG + X_SIZE;      // 32 slots x 128
constexpr int WS_ESSQS = WS_ESUMS + 32 * H;
constexpr int WS_NSUMS = WS_ESSQS + 32 * H;    // 8 slots x 128
constexpr int WS_NSSQS = WS_NSUMS + 8 * H;
constexpr int WS_STAT_END = WS_NSSQS + 8 * H;
constexpr int WS_ESC   = WS_STAT_END;
constexpr int WS_ESH   = WS_ESC + H;
constexpr int WS_NSC   = WS_ESH + H;
constexpr int WS_NSH   = WS_NSC + H;
constexpr int WS_ETMP  = WS_NSH + H;           // bf16 area (2B/elem), 16B-aligned
constexpr size_t NEED_WS_BYTES = (size_t)WS_ETMP * 4 + (size_t)E_ELEMS * 2;

__device__ __forceinline__ unsigned short f2bf(float f) {
  __hip_bfloat16 h = __float2bfloat16(f);
  return __builtin_bit_cast(unsigned short, h);
}

__device__ __forceinline__ short8 pack8(float4 a, float4 b) {
  short8 r;
  r[0] = (short)f2bf(a.x); r[1] = (short)f2bf(a.y);
  r[2] = (short)f2bf(a.z); r[3] = (short)f2bf(a.w);
  r[4] = (short)f2bf(b.x); r[5] = (short)f2bf(b.y);
  r[6] = (short)f2bf(b.z); r[7] = (short)f2bf(b.w);
  return r;
}

// ---- node linears: Vx, Ux, Vxn (masked) ----
__global__ __launch_bounds__(128) void k_prep(
    const float* __restrict__ x, const int* __restrict__ mask,
    const float* __restrict__ VeW, const float* __restrict__ Veb,
    const float* __restrict__ UnW, const float* __restrict__ Unb,
    const float* __restrict__ VnW, const float* __restrict__ Vnb,
    float* __restrict__ ws) {
  const int bi = blockIdx.x, h = threadIdx.x;
  __shared__ float xr[H];
  xr[h] = x[bi * H + h];
  __syncthreads();
  const float mi = (float)mask[bi];
  float a0 = 0.f, a1 = 0.f, a2 = 0.f;
  #pragma unroll 4
  for (int k = 0; k < H; k += 4) {
    const float x0 = xr[k], x1 = xr[k + 1], x2 = xr[k + 2], x3 = xr[k + 3];
    float4 w;
    w = *(const float4*)&VeW[h * H + k];
    a0 += w.x * x0 + w.y * x1 + w.z * x2 + w.w * x3;
    w = *(const float4*)&UnW[h * H + k];
    a1 += w.x * x0 + w.y * x1 + w.z * x2 + w.w * x3;
    w = *(const float4*)&VnW[h * H + k];
    a2 += w.x * x0 + w.y * x1 + w.z * x2 + w.w * x3;
  }
  ws[WS_VX  + bi * H + h] = mi * (a0 + Veb[h]);
  ws[WS_UX  + bi * H + h] = mi * (a1 + Unb[h]);
  ws[WS_VXN + bi * H + h] = mi * (a2 + Vnb[h]);
}

// ---- pass 0: GEMM (Ue@e) + stats + sigmoid aggregation (+ optional e_tmp store) ----
// Block = one (b,i). 4 waves, wave w owns h-quarter [32w, 32w+32).
// e-tile (16 rows x 128) staged ONCE per block via global_load_lds, double-buffered,
// source-pre-swizzled (16B chunk index ^= row&7) so ds_read_b128 is conflict-light.
template <int STORE_ETMP>
__global__ __launch_bounds__(256) void k_edge0(
    const float* __restrict__ e, const int* __restrict__ mask,
    const float* __restrict__ UeW, const float* __restrict__ Ueb,
    float* __restrict__ ws, unsigned short* __restrict__ etmp) {
  const int bi = blockIdx.x;
  const int b = bi / N;
  const int tid = threadIdx.x;
  const int w = tid >> 6, lane = tid & 63;
  const int l15 = lane & 15, lg = lane >> 4;
  const int hbase = w * 32;

  __shared__ float etile[2][16 * 128];   // 16 KB, swizzled-linear
  __shared__ float mrow[N];
  __shared__ float pS[4][32], pS2[4][32], pA[4][32];

  if (tid < N) mrow[tid] = (float)mask[b * N + tid];

  const float mi = (float)mask[bi];
  const float* __restrict__ eg = e + (size_t)bi * NH;

  // W frags: lane holds W[hbase+ht*16+l15][s*32 + lg*8 + (0..7)] as bf16 (B-operand)
  short8 Wf[2][4];
  #pragma unroll
  for (int ht = 0; ht < 2; ++ht) {
    const float* wr = &UeW[(size_t)(hbase + ht * 16 + l15) * H + lg * 8];
    #pragma unroll
    for (int s = 0; s < 4; ++s) {
      const float4 u0 = *(const float4*)(wr + s * 32);
      const float4 u1 = *(const float4*)(wr + s * 32 + 4);
      Wf[ht][s] = pack8(u0, u1);
    }
  }

  float basev[2];
  #pragma unroll
  for (int ht = 0; ht < 2; ++ht) {
    const int h = hbase + ht * 16 + l15;
    basev[ht] = Ueb[h] + ws[WS_VX + (size_t)bi * H + h];
  }

  float bnS[2] = {0.f, 0.f}, bnS2[2] = {0.f, 0.f}, ag[2] = {0.f, 0.f};

  // stage: wave w issues 2 global_load_lds (rows 4w..4w+3) for tile jt into buf
  auto stage = [&](int buf, int jt) {
    const int j0 = jt * 16;
    #pragma unroll
    for (int ii = 0; ii < 2; ++ii) {
      const int instr = 2 * w + ii;
      const int row = 2 * instr + (lane >> 5);    // 0..15
      const int c16 = lane & 31;                  // 16B chunk within row
      const int gr = min(j0 + row, N - 1);        // clamp (avoid OOB on last tile)
      const int sc16 = c16 ^ (row & 7);           // pre-swizzled source chunk
      const float* src = eg + (size_t)gr * H + sc16 * 4;
      float* dst = &etile[buf][instr * 256];      // wave-uniform; HW adds lane*16B
      __builtin_amdgcn_global_load_lds(
          (const __attribute__((address_space(1))) void*)src,
          (__attribute__((address_space(3))) void*)dst, 16, 0, 0);
    }
  };

  stage(0, 0);

  for (int jt = 0; jt < 13; ++jt) {
    const int cur = jt & 1;
    if (jt < 12) stage(cur ^ 1, jt + 1);
    __syncthreads();   // drains vmcnt: etile[cur] (and prefetch) complete; all waves synced

    const int j0 = jt * 16;
    const float* tp = &etile[cur][0];

    // read my fragments (swizzled): lane wants row l15, floats lg*8 + s*32
    short8 Ef[4];
    #pragma unroll
    for (int s = 0; s < 4; ++s) {
      const int c0 = (lg * 2 + s * 8) ^ (l15 & 7);
      const int c1 = (lg * 2 + s * 8 + 1) ^ (l15 & 7);
      const float4 u0 = *(const float4*)&tp[l15 * 128 + c0 * 4];
      const float4 u1 = *(const float4*)&tp[l15 * 128 + c1 * 4];
      Ef[s] = pack8(u0, u1);
    }

    f32x4 acc[2] = {f32x4(0.f), f32x4(0.f)};
    #pragma unroll
    for (int s = 0; s < 4; ++s) {
      #pragma unroll
      for (int ht = 0; ht < 2; ++ht)   // D[j][h]: col h = ht*16+l15, row j = j0+4*lg+r
        acc[ht] = __builtin_amdgcn_mfma_f32_16x16x32_bf16(Ef[s], Wf[ht][s], acc[ht], 0, 0, 0);
    }

    #pragma unroll
    for (int r = 0; r < 4; ++r) {
      const int j = j0 + 4 * lg + r;
      const bool valid = (j < N);
      const int jc = valid ? j : N - 1;
      const float msk = valid ? mi * mrow[jc] : 0.f;
      const size_t row = (size_t)(b * N + jc) * H;
      #pragma unroll
      for (int ht = 0; ht < 2; ++ht) {
        const int h = hbase + ht * 16 + l15;
        const float vx = ws[WS_VX + row + h];
        const float vxn = ws[WS_VXN + row + h];
        const float v = acc[ht][r] + basev[ht] + vx;
        bnS[ht]  += msk * v;
        bnS2[ht] += msk * v * v;
        const float sg = __builtin_amdgcn_rcpf(1.f + __expf(-v));
        ag[ht] += msk * sg * vxn;
        if (STORE_ETMP && valid)
          etmp[(size_t)bi * NH + (size_t)j * H + h] = f2bf(v);
      }
    }
    __syncthreads();   // all waves done reading etile[cur] before restage
  }

  // reduce over lg (lane bits 4,5); each l15 then holds the sum for its h
  #pragma unroll
  for (int ht = 0; ht < 2; ++ht) {
    bnS[ht]  += __shfl_xor(bnS[ht], 16);  bnS[ht]  += __shfl_xor(bnS[ht], 32);
    bnS2[ht] += __shfl_xor(bnS2[ht], 16); bnS2[ht] += __shfl_xor(bnS2[ht], 32);
    ag[ht]   += __shfl_xor(ag[ht], 16);   ag[ht]   += __shfl_xor(ag[ht], 32);
  }
  if (lg == 0) {
    #pragma unroll
    for (int ht = 0; ht < 2; ++ht) {
      pS[w][ht * 16 + l15] = bnS[ht];
      pS2[w][ht * 16 + l15] = bnS2[ht];
      pA[w][ht * 16 + l15] = ag[ht];
    }
  }
  __syncthreads();
  if (tid < H) {
    const int w2 = tid >> 5, idx = tid & 31;   // h-quarters are disjoint: single partial
    const int slot = (bi & 31) * H + tid;
    atomicAdd(&ws[WS_ESUMS + slot], pS[w2][idx]);
    atomicAdd(&ws[WS_ESSQS + slot], pS2[w2][idx]);
    ws[WS_AGG + (size_t)bi * H + tid] = pA[w2][idx];   // block-unique: plain store
  }
}

// ---- x_tmp = Ux + agg; node BN partial sums (slotted) ----
__global__ void k_x1(const int* __restrict__ mask, float* __restrict__ ws) {
  const int t = blockIdx.x * 256 + threadIdx.x;   // 50*256 = 12800
  const int h = t & 127, g = t >> 7;              // g 0..99
  float s = 0.f, s2 = 0.f;
  for (int bi = g; bi < BN; bi += 100) {
    const float v = ws[WS_UX + bi * H + h] + ws[WS_AGG + bi * H + h];
    ws[WS_XTMP + bi * H + h] = v;
    if (mask[bi] != 0) { s += v; s2 += v * v; }
  }
  atomicAdd(&ws[WS_NSUMS + (g & 7) * H + h], s);
  atomicAdd(&ws[WS_NSSQS + (g & 7) * H + h], s2);
}

// ---- counts + finalize BN scale/shift for edge and node ----
__global__ void k_stats(const int* __restrict__ mask,
                        const float* __restrict__ beg, const float* __restrict__ beb,
                        const float* __restrict__ bng, const float* __restrict__ bnb,
                        float* __restrict__ ws) {
  __shared__ float sb[8];
  const int t = threadIdx.x;          // 256 threads
  const int b = t >> 5, li = t & 31;
  float s = 0.f;
  for (int i = li; i < N; i += 32) s += (float)mask[b * N + i];
  #pragma unroll
  for (int o = 16; o >= 1; o >>= 1) s += __shfl_down(s, o, 32);
  if (li == 0) sb[b] = s;
  __syncthreads();
  if (t < H) {
    float cn = 0.f, ce = 0.f;
    #pragma unroll
    for (int bb = 0; bb < 8; ++bb) { cn += sb[bb]; ce += sb[bb] * sb[bb]; }
    ce = fmaxf(ce, 1.f); cn = fmaxf(cn, 1.f);
    float es = 0.f, es2 = 0.f;
    #pragma unroll 4
    for (int k = 0; k < 32; ++k) { es += ws[WS_ESUMS + k * H + t]; es2 += ws[WS_ESSQS + k * H + t]; }
    float ns = 0.f, ns2 = 0.f;
    #pragma unroll
    for (int k = 0; k < 8; ++k) { ns += ws[WS_NSUMS + k * H + t]; ns2 += ws[WS_NSSQS + k * H + t]; }
    const float me = es / ce;
    const float ve = fmaxf(es2 / ce - me * me, 0.f);
    const float se = rsqrtf(ve + 1e-5f) * beg[t];
    ws[WS_ESC + t] = se;
    ws[WS_ESH + t] = beb[t] - me * se;
    const float mn = ns / cn;
    const float vn = fmaxf(ns2 / cn - mn * mn, 0.f);
    const float sn = rsqrtf(vn + 1e-5f) * bng[t];
    ws[WS_NSC + t] = sn;
    ws[WS_NSH + t] = bnb[t] - mn * sn;
  }
}

// ---- x_new = x + relu(masked BN(x_tmp)) ----
__global__ void k_x2(const float* __restrict__ x, const int* __restrict__ mask,
                     const float* __restrict__ ws, float* __restrict__ out) {
  const int idx = blockIdx.x * 256 + threadIdx.x;
  if (idx >= X_SIZE) return;
  const int h = idx & 127, bi = idx >> 7;
  const float v = ws[WS_XTMP + idx];
  const float r = (mask[bi] != 0) ? (v * ws[WS_NSC + h] + ws[WS_NSH + h]) : v;
  out[idx] = x[idx] + fmaxf(r, 0.f);
}

// ---- e_new = e + relu(masked BN(e_tmp)) : pure streaming elementwise ----
__global__ __launch_bounds__(256) void k_efin(
    const float* __restrict__ e, const int* __restrict__ mask,
    const float* __restrict__ ws, const unsigned short* __restrict__ etmp,
    float* __restrict__ out) {
  const int t = blockIdx.x * 256 + threadIdx.x;   // 5,120,000 threads, 8 elems each
  const int bi = t / 3200;                        // NH/8
  const int rem = t - bi * 3200;
  const int j = rem >> 4;
  const int h0 = (rem & 15) * 8;
  const int b = bi / N;
  const bool on = (mask[bi] & mask[b * N + j]) != 0;

  const size_t base = (size_t)t * 8;
  const ushort4 p0 = *(const ushort4*)&etmp[base];
  const ushort4 p1 = *(const ushort4*)&etmp[base + 4];
  const float4 e0 = *(const float4*)&e[base];
  const float4 e1 = *(const float4*)&e[base + 4];
  const float4 sc0 = *(const float4*)&ws[WS_ESC + h0];
  const float4 sc1 = *(const float4*)&ws[WS_ESC + h0 + 4];
  const float4 sh0 = *(const float4*)&ws[WS_ESH + h0];
  const float4 sh1 = *(const float4*)&ws[WS_ESH + h0 + 4];

  const unsigned short pv[8] = {(unsigned short)p0.x, (unsigned short)p0.y,
                                (unsigned short)p0.z, (unsigned short)p0.w,
                                (unsigned short)p1.x, (unsigned short)p1.y,
                                (unsigned short)p1.z, (unsigned short)p1.w};
  const float ev[8] = {e0.x, e0.y, e0.z, e0.w, e1.x, e1.y, e1.z, e1.w};
  const float scv[8] = {sc0.x, sc0.y, sc0.z, sc0.w, sc1.x, sc1.y, sc1.z, sc1.w};
  const float shv[8] = {sh0.x, sh0.y, sh0.z, sh0.w, sh1.x, sh1.y, sh1.z, sh1.w};

  float o[8];
  #pragma unroll
  for (int k = 0; k < 8; ++k) {
    const float v = __uint_as_float(((unsigned)pv[k]) << 16);
    const float r = on ? (v * scv[k] + shv[k]) : v;
    o[k] = ev[k] + fmaxf(r, 0.f);
  }
  float* og = out + X_SIZE;
  *(float4*)&og[base]     = make_float4(o[0], o[1], o[2], o[3]);
  *(float4*)&og[base + 4] = make_float4(o[4], o[5], o[6], o[7]);
}

// ---- fallback pass 1 (recompute; used only if ws too small for e_tmp) ----
__global__ __launch_bounds__(256) void k_erec(
    const float* __restrict__ e, const int* __restrict__ mask,
    const float* __restrict__ UeW, const float* __restrict__ Ueb,
    float* __restrict__ ws, float* __restrict__ out) {
  const int bi = blockIdx.x;
  const int b = bi / N;
  const int tid = threadIdx.x;
  const int w = tid >> 6, lane = tid & 63;
  const int l15 = lane & 15, lg = lane >> 4;
  const int hbase = (w & 1) * 64;

  __shared__ float mrow[N];
  if (tid < N) mrow[tid] = (float)mask[b * N + tid];
  __syncthreads();

  const float mi = (float)mask[bi];
  const float* __restrict__ eg = e + (size_t)bi * NH;

  short8 Wf[4][4];
  #pragma unroll
  for (int ht = 0; ht < 4; ++ht) {
    const float* wr = &UeW[(size_t)(hbase + ht * 16 + l15) * H + lg * 8];
    #pragma unroll
    for (int s = 0; s < 4; ++s) {
      const float4 u0 = *(const float4*)(wr + s * 32);
      const float4 u1 = *(const float4*)(wr + s * 32 + 4);
      Wf[ht][s] = pack8(u0, u1);
    }
  }
  float4 base4[4], sc4[4], sh4[4];
  #pragma unroll
  for (int ht = 0; ht < 4; ++ht) {
    const int h0 = hbase + ht * 16 + 4 * lg;
    const float4 ub = *(const float4*)&Ueb[h0];
    const float4 vx = *(const float4*)&ws[WS_VX + (size_t)bi * H + h0];
    base4[ht] = make_float4(ub.x + vx.x, ub.y + vx.y, ub.z + vx.z, ub.w + vx.w);
    sc4[ht] = *(const float4*)&ws[WS_ESC + h0];
    sh4[ht] = *(const float4*)&ws[WS_ESH + h0];
  }
  const short8 zfrag = {0, 0, 0, 0, 0, 0, 0, 0};
  for (int jt = (w >> 1); jt < 13; jt += 2) {
    const int j0 = jt * 16;
    const int jl = j0 + l15;
    const float* er = eg + (size_t)(jl < N ? jl : 0) * H + lg * 8;
    short8 Ef[4];
    #pragma unroll
    for (int s = 0; s < 4; ++s) {
      const float4 u0 = *(const float4*)(er + s * 32);
      const float4 u1 = *(const float4*)(er + s * 32 + 4);
      Ef[s] = pack8(u0, u1);
    }
    if (jl >= N) {
      #pragma unroll
      for (int s = 0; s < 4; ++s) Ef[s] = zfrag;
    }
    f32x4 acc[4] = {f32x4(0.f), f32x4(0.f), f32x4(0.f), f32x4(0.f)};
    #pragma unroll
    for (int s = 0; s < 4; ++s) {
      #pragma unroll
      for (int ht = 0; ht < 4; ++ht)
        acc[ht] = __builtin_amdgcn_mfma_f32_16x16x32_bf16(Wf[ht][s], Ef[s], acc[ht], 0, 0, 0);
    }
    const int j = j0 + l15;
    if (j < N) {
      const float msk = mi * mrow[j];
      const size_t vrow = (size_t)(b * N + j) * H;
      const size_t erow = (size_t)j * H;
      float* __restrict__ og = out + (size_t)X_SIZE + (size_t)bi * NH + erow;
      #pragma unroll
      for (int ht = 0; ht < 4; ++ht) {
        const int h0 = hbase + ht * 16 + 4 * lg;
        const float4 vx4 = *(const float4*)&ws[WS_VX + vrow + h0];
        const float4 eo4 = *(const float4*)&eg[erow + h0];
        const float vv[4] = {acc[ht][0] + base4[ht].x + vx4.x,
                             acc[ht][1] + base4[ht].y + vx4.y,
                             acc[ht][2] + base4[ht].z + vx4.z,
                             acc[ht][3] + base4[ht].w + vx4.w};
        const float scv[4] = {sc4[ht].x, sc4[ht].y, sc4[ht].z, sc4[ht].w};
        const float shv[4] = {sh4[ht].x, sh4[ht].y, sh4[ht].z, sh4[ht].w};
        const float ev[4] = {eo4.x, eo4.y, eo4.z, eo4.w};
        float o[4];
        #pragma unroll
        for (int r = 0; r < 4; ++r) {
          const float rr = (msk > 0.f) ? (vv[r] * scv[r] + shv[r]) : vv[r];
          o[r] = ev[r] + fmaxf(rr, 0.f);
        }
        *(float4*)&og[h0] = make_float4(o[0], o[1], o[2], o[3]);
      }
    }
  }
}

}  // namespace

extern "C" void kernel_launch(void* const* d_in, const int* in_sizes, int n_in,
                              void* d_out, int out_size, void* d_ws, size_t ws_size,
                              hipStream_t stream) {
  const float* x    = (const float*)d_in[0];
  const float* e    = (const float*)d_in[1];
  const int*   mask = (const int*)d_in[2];
  const float* UeW  = (const float*)d_in[3];
  const float* Ueb  = (const float*)d_in[4];
  const float* VeW  = (const float*)d_in[5];
  const float* Veb  = (const float*)d_in[6];
  const float* UnW  = (const float*)d_in[7];
  const float* Unb  = (const float*)d_in[8];
  const float* VnW  = (const float*)d_in[9];
  const float* Vnb  = (const float*)d_in[10];
  const float* bng  = (const float*)d_in[11];
  const float* bnb  = (const float*)d_in[12];
  const float* beg  = (const float*)d_in[13];
  const float* beb  = (const float*)d_in[14];
  float* ws  = (float*)d_ws;
  float* out = (float*)d_out;
  unsigned short* etmp = (unsigned short*)(ws + WS_ETMP);
  const bool have_ws = (ws_size >= NEED_WS_BYTES);

  // zero the slotted stat accumulators (contiguous region)
  hipMemsetAsync(ws + WS_ESUMS, 0, (WS_STAT_END - WS_ESUMS) * sizeof(float), stream);
  k_prep<<<BN, 128, 0, stream>>>(x, mask, VeW, Veb, UnW, Unb, VnW, Vnb, ws);
  if (have_ws)
    k_edge0<1><<<BN, 256, 0, stream>>>(e, mask, UeW, Ueb, ws, etmp);
  else
    k_edge0<0><<<BN, 256, 0, stream>>>(e, mask, UeW, Ueb, ws, etmp);
  k_x1<<<50, 256, 0, stream>>>(mask, ws);
  k_stats<<<1, 256, 0, stream>>>(mask, beg, beb, bng, bnb, ws);
  k_x2<<<800, 256, 0, stream>>>(x, mask, ws, out);
  if (have_ws)
    k_efin<<<20000, 256, 0, stream>>>(e, mask, ws, etmp, out);
  else
    k_erec<<<BN, 256, 0, stream>>>(e, mask, UeW, Ueb, ws, out);
}